// Round 5
// baseline (189.831 us; speedup 1.0000x reference)
//
#include <hip/hip_runtime.h>
#include <hip/hip_bf16.h>

// HyConv round 12: fix self-inflicted locality wounds + surface phase counters.
//  (a) x_edge stored with PLAIN stores (round-9/11's NT store streamed phase2's
//      gather source to HBM — 164MB of reuse-16 reads first-touching at ~900cy).
//      NT kept only on `out` (nothing reads it).
//  (b) gemm chunk->XCD affinity: batch b's xt rows computed on XCD pair {2b,2b+1},
//      the same pair phase1 reads them on (tests cross-kernel L2 retention too).
//  (c) build: 4 edges/thread (int4 H loads, 8 independent atomic->store chains) for
//      2x atomic MLP; 625 build blocks exactly cover 640k edges.
//  Grid 1888: per XCD, slots interleave gemm/build for latency overlap.
// memset(ctr) -> build_gemm -> phase1_pull(+B compact) -> phase2_pull

#define BB 4
#define NN 10000
#define MM 10000
#define EE 160000
#define CC 128
#define BM (BB * MM)   // 40000 hyperedge buckets
#define BN (BB * NN)   // 40000 node buckets
#define NCOPY 8
#define CAPX 16        // per-copy bucket capacity; per-copy deg ~ Poisson(2), P[>=17]~5e-11

typedef unsigned short u16;
using bf16 = __hip_bfloat16;
using bf162 = __hip_bfloat162;
typedef unsigned u32x4 __attribute__((ext_vector_type(4)));
typedef float f32x4 __attribute__((ext_vector_type(4)));

// ---------------- fused: gemm || build, XCD-aware slot mapping ----------------
// Per XCD x (bi&7), slot = bi>>3 (0..235):
//   slot<158: even slot -> gemm ordinal k=slot/2 (79), odd -> build ordinal k (79)
//   slot>=158: gemm ordinal 79+(slot-158) (78)   => 157 gemm + 79 build per XCD.
// gemm: batch b = x>>1, chunk c = 2k + (x&1) (c<313; chunk 312 is 16 rows) ->
//       batch-b xt rows produced on XCD pair {2b,2b+1} (phase1 affinity match).
// build: work id w = k*8+x (w<625), 4 edges/thread, copy = x (XCD-local atomics).
__global__ __launch_bounds__(256) void build_gemm_k(const int* __restrict__ H,
                                                    int* __restrict__ ctr,
                                                    u16* __restrict__ srcA,
                                                    u16* __restrict__ srcB,
                                                    const float* __restrict__ x,
                                                    const float* __restrict__ theta,
                                                    bf16* __restrict__ xt) {
    __shared__ float sTh[64 * 128];  // 32 KB
    __shared__ float sX[32 * 128];   // 16 KB
    const int bi = blockIdx.x;
    const int xcd = bi & 7;
    const int slot = bi >> 3;
    bool is_gemm;
    int k;
    if (slot < 158) { is_gemm = ((slot & 1) == 0); k = slot >> 1; }
    else            { is_gemm = true;              k = 79 + (slot - 158); }

    if (!is_gemm) {
        // ---- build: 4 edges per thread, XCD-local copy = xcd ----
        const int w = k * 8 + xcd;
        if (w >= 625) return;
        const int g0 = (w * 256 + (int)threadIdx.x) * 4;  // 4-aligned, same batch
        const int cp = xcd;
        const int b = g0 / EE, e = g0 - b * EE;
        const int4 nd4 = *(const int4*)&H[b * 2 * EE + e];
        const int4 he4 = *(const int4*)&H[b * 2 * EE + EE + e];
        const int nd[4] = {nd4.x, nd4.y, nd4.z, nd4.w};
        const int he[4] = {he4.x, he4.y, he4.z, he4.w};
#pragma unroll
        for (int t = 0; t < 4; ++t) {
            const int bktA = b * MM + he[t];
            const int s = atomicAdd(&ctr[cp * (BM + BN) + bktA], 1);
            if (s < CAPX) srcA[((size_t)cp * BM + bktA) * CAPX + s] = (u16)nd[t];
        }
#pragma unroll
        for (int t = 0; t < 4; ++t) {
            const int bktB = b * NN + nd[t];
            const int q = atomicAdd(&ctr[cp * (BM + BN) + BM + bktB], 1);
            if (q < CAPX) srcB[((size_t)cp * BN + bktB) * CAPX + q] = (u16)he[t];
        }
        return;
    }

    // ---- gemm: chunk of <=32 rows x 128 cols; thread = 8 rows x 2 cols ----
    const int c = 2 * k + (xcd & 1);
    if (c >= 313) return;
    const int b = xcd >> 1;
    const int row0 = b * NN + c * 32;
    const int nr = (c == 312) ? 16 : 32;  // last chunk: 16 rows
    const int tid = threadIdx.x;
    {
        const float4* src = (const float4*)&x[(size_t)row0 * 128];
        float4* dst = (float4*)sX;
        const int lim = nr * 32;  // float4 count
#pragma unroll
        for (int i = 0; i < 4; ++i)
            if (tid + 256 * i < lim) dst[tid + 256 * i] = src[tid + 256 * i];
    }
    const int cg2 = (tid & 63) * 2;  // column pair base (0..126)
    const int rg = tid >> 6;         // row group 0..3
    float ax[8], ay[8];
#pragma unroll
    for (int r = 0; r < 8; ++r) { ax[r] = 0.f; ay[r] = 0.f; }

    for (int half = 0; half < 2; ++half) {
        __syncthreads();
        {
            const float4* src = (const float4*)&theta[half * 64 * 128];
            float4* dst = (float4*)sTh;
#pragma unroll
            for (int i = 0; i < 8; ++i) dst[tid + 256 * i] = src[tid + 256 * i];
        }
        __syncthreads();
#pragma unroll
        for (int k4 = 0; k4 < 16; ++k4) {
            const int kk = 4 * k4;
            const float2 t0 = *(const float2*)&sTh[(kk + 0) * 128 + cg2];
            const float2 t1 = *(const float2*)&sTh[(kk + 1) * 128 + cg2];
            const float2 t2 = *(const float2*)&sTh[(kk + 2) * 128 + cg2];
            const float2 t3 = *(const float2*)&sTh[(kk + 3) * 128 + cg2];
#pragma unroll
            for (int r = 0; r < 8; ++r) {
                const float4 xv =
                    *(const float4*)&sX[(rg * 8 + r) * 128 + half * 64 + kk];
                ax[r] = fmaf(xv.x, t0.x, ax[r]); ay[r] = fmaf(xv.x, t0.y, ay[r]);
                ax[r] = fmaf(xv.y, t1.x, ax[r]); ay[r] = fmaf(xv.y, t1.y, ay[r]);
                ax[r] = fmaf(xv.z, t2.x, ax[r]); ay[r] = fmaf(xv.z, t2.y, ay[r]);
                ax[r] = fmaf(xv.w, t3.x, ax[r]); ay[r] = fmaf(xv.w, t3.y, ay[r]);
            }
        }
    }
#pragma unroll
    for (int r = 0; r < 8; ++r) {
        if (rg * 8 + r < nr) {
            bf162 h;
            h.x = __float2bfloat16(ax[r]);
            h.y = __float2bfloat16(ay[r]);
            *(bf162*)&xt[(size_t)(row0 + rg * 8 + r) * 128 + cg2] = h;
        }
    }
}

// ---------------- bf16-pair helpers ----------------
__device__ __forceinline__ float blo(unsigned w) { return __uint_as_float(w << 16); }
__device__ __forceinline__ float bhi(unsigned w) { return __uint_as_float(w & 0xffff0000u); }
__device__ __forceinline__ unsigned pk2(float a, float b) {
    bf162 h;
    h.x = __float2bfloat16(a);
    h.y = __float2bfloat16(b);
    return *(unsigned*)&h;
}

// accumulate 8 channels from a 16B chunk of one row
__device__ __forceinline__ void acc8(const uint4 pk, float* s) {
    s[0] += blo(pk.x); s[1] += bhi(pk.x);
    s[2] += blo(pk.y); s[3] += bhi(pk.y);
    s[4] += blo(pk.z); s[5] += bhi(pk.z);
    s[6] += blo(pk.w); s[7] += bhi(pk.w);
}

// XCD batch-affinity swizzle: batch b -> XCD pair {2b,2b+1}; bijective.
__device__ __forceinline__ void swz_bucket(int blk, int tid, int& b, int& wid_local4) {
    const int xcd = blk & 7;
    b = xcd >> 1;                                   // batch 0..3
    const int jj = ((blk >> 3) << 1) | (xcd & 1);   // 0..2499
    wid_local4 = jj * 4 + (tid >> 6);               // bucket within batch
}

// ---------------- phase1: x_edge[bkt] = mean over incident nodes of xt --------------
// Also compacts the 8 B-side copy lists for node bucket (b, wl) into flatB/cntB.
__global__ __launch_bounds__(256) void phase1_pull(const bf16* __restrict__ xt,
                                                   const int* __restrict__ ctr,
                                                   const u16* __restrict__ srcA,
                                                   const u16* __restrict__ srcB,
                                                   u16* __restrict__ flatB,
                                                   int* __restrict__ cntB,
                                                   bf16* __restrict__ x_edge) {
    __shared__ __align__(16) u16 bufA[4 * 64];
    __shared__ __align__(16) u16 bufB[4 * 64];
    int b, wl;
    swz_bucket(blockIdx.x, threadIdx.x, b, wl);
    const int widA = b * MM + wl;                   // hyperedge bucket
    const int widB = b * NN + wl;                   // node bucket (same local index)
    const int lane = threadIdx.x & 63;
    const int w4 = threadIdx.x >> 6;
    u16* wbufA = &bufA[w4 * 64];
    u16* wbufB = &bufB[w4 * 64];

    // issue ALL remote loads up-front (frags unconditional; ctr in parallel)
    int cA = 0, cB = 0;
    uint4 a0, a1, b0, b1;
    if (lane < NCOPY) {
        const u16* la = srcA + ((size_t)lane * BM + widA) * CAPX;
        const u16* lb = srcB + ((size_t)lane * BN + widB) * CAPX;
        a0 = *(const uint4*)la; a1 = *(const uint4*)(la + 8);
        b0 = *(const uint4*)lb; b1 = *(const uint4*)(lb + 8);
        cA = ctr[lane * (BM + BN) + widA];       cA = cA > CAPX ? CAPX : cA;
        cB = ctr[lane * (BM + BN) + BM + widB];  cB = cB > CAPX ? CAPX : cB;
    }
    int pA = cA, pB = cB;  // inclusive prefixes over lanes 0..7
#pragma unroll
    for (int d = 1; d < 8; d <<= 1) {
        const int oA = __shfl_up(pA, d, 64);
        const int oB = __shfl_up(pB, d, 64);
        if (lane >= d) { pA += oA; pB += oB; }
    }
    const int baseA = pA - cA, baseB = pB - cB;
    int totA = __shfl(pA, 7, 64); totA = totA > 64 ? 64 : totA;
    int totB = __shfl(pB, 7, 64); totB = totB > 64 ? 64 : totB;
    if (lane < NCOPY) {
        const unsigned wa[8] = {a0.x, a0.y, a0.z, a0.w, a1.x, a1.y, a1.z, a1.w};
        const unsigned wb[8] = {b0.x, b0.y, b0.z, b0.w, b1.x, b1.y, b1.z, b1.w};
#pragma unroll
        for (int j = 0; j < CAPX; ++j) {
            const u16 va = (u16)((j & 1) ? (wa[j >> 1] >> 16) : (wa[j >> 1] & 0xffffu));
            const u16 vb = (u16)((j & 1) ? (wb[j >> 1] >> 16) : (wb[j >> 1] & 0xffffu));
            const int pa = baseA + j, pb = baseB + j;
            if (j < cA && pa < 64) wbufA[pa] = va;
            if (j < cB && pb < 64) wbufB[pb] = vb;
        }
    }
    __syncthreads();  // publish both LDS lists

    // publish flat B record (128B; plain stores — consumer-local)
    if (lane < 8)
        *(u32x4*)&flatB[(size_t)widB * 64 + lane * 8] = *(const u32x4*)&wbufB[lane * 8];
    if (lane == 0) cntB[widB] = totB;

    // gather A: lane reads uint4 (8 channels); 64 lanes cover 4 rows/load
    const bf16* base = xt + (size_t)b * NN * CC;
    const int g = lane >> 4;     // row-group 0..3
    const int c16 = lane & 15;   // 16B chunk -> channels c16*8 .. +8
    float s[8];
#pragma unroll
    for (int k = 0; k < 8; ++k) s[k] = 0.f;
    int i = 0;
    for (; i + 4 <= totA; i += 4) {
        const int idx = wbufA[i + g];
        const uint4 pk = *(const uint4*)(base + (size_t)idx * CC + c16 * 8);
        acc8(pk, s);
    }
    if (i < totA && g < totA - i) {
        const int idx = wbufA[i + g];
        const uint4 pk = *(const uint4*)(base + (size_t)idx * CC + c16 * 8);
        acc8(pk, s);
    }
#pragma unroll
    for (int k = 0; k < 8; ++k) {
        s[k] += __shfl_xor(s[k], 16, 64);
        s[k] += __shfl_xor(s[k], 32, 64);
    }
    const float w = totA ? 1.0f / (float)totA : 0.f;
    if (g == 0) {
        u32x4 o;
        o.x = pk2(s[0] * w, s[1] * w);
        o.y = pk2(s[2] * w, s[3] * w);
        o.z = pk2(s[4] * w, s[5] * w);
        o.w = pk2(s[6] * w, s[7] * w);
        // PLAIN store: same XCD pair re-reads this in phase2 (16x reuse) — cache it.
        *(u32x4*)&x_edge[(size_t)widA * CC + c16 * 8] = o;
    }
}

// ---------------- phase2: out[bkt] = mean over incident hyperedges + bias -----------
__global__ __launch_bounds__(256) void phase2_pull(const bf16* __restrict__ x_edge,
                                                   const u16* __restrict__ flatB,
                                                   const int* __restrict__ cntB,
                                                   const float* __restrict__ bias,
                                                   float* __restrict__ out) {
    __shared__ __align__(16) u16 buf[4 * 64];
    int b, wl;
    swz_bucket(blockIdx.x, threadIdx.x, b, wl);
    const int wid = b * NN + wl;
    const int lane = threadIdx.x & 63;
    u16* wbuf = &buf[(threadIdx.x >> 6) * 64];
    const int t0 = cntB[wid];  // broadcast read
    if (lane < 8)
        *(u32x4*)&wbuf[lane * 8] = *(const u32x4*)&flatB[(size_t)wid * 64 + lane * 8];
    __syncthreads();
    const int total = t0 > 64 ? 64 : t0;

    const bf16* base = x_edge + (size_t)b * MM * CC;  // same XCD pair wrote this slice
    const int g = lane >> 4;
    const int c16 = lane & 15;
    float s[8];
#pragma unroll
    for (int k = 0; k < 8; ++k) s[k] = 0.f;
    int i = 0;
    for (; i + 4 <= total; i += 4) {
        const int idx = wbuf[i + g];
        const uint4 pk = *(const uint4*)(base + (size_t)idx * CC + c16 * 8);
        acc8(pk, s);
    }
    if (i < total && g < total - i) {
        const int idx = wbuf[i + g];
        const uint4 pk = *(const uint4*)(base + (size_t)idx * CC + c16 * 8);
        acc8(pk, s);
    }
#pragma unroll
    for (int k = 0; k < 8; ++k) {
        s[k] += __shfl_xor(s[k], 16, 64);
        s[k] += __shfl_xor(s[k], 32, 64);
    }
    const float w = total ? 1.0f / (float)total : 0.f;
    if (g < 2) {
        const float4 bv = *(const float4*)&bias[c16 * 8 + g * 4];
        f32x4 o;
        if (g == 0) {
            o.x = s[0] * w + bv.x; o.y = s[1] * w + bv.y;
            o.z = s[2] * w + bv.z; o.w = s[3] * w + bv.w;
        } else {
            o.x = s[4] * w + bv.x; o.y = s[5] * w + bv.y;
            o.z = s[6] * w + bv.z; o.w = s[7] * w + bv.w;
        }
        // out is final output — NT is safe and keeps it from evicting gather lines.
        __builtin_nontemporal_store(o, (f32x4*)&out[(size_t)wid * CC + c16 * 8 + g * 4]);
    }
}

extern "C" void kernel_launch(void* const* d_in, const int* in_sizes, int n_in,
                              void* d_out, int out_size, void* d_ws, size_t ws_size,
                              hipStream_t stream) {
    const float* x = (const float*)d_in[0];
    const int* H = (const int*)d_in[1];
    const float* theta = (const float*)d_in[2];
    const float* bias = (const float*)d_in[3];
    float* out = (float*)d_out;

    // workspace (~48.8 MB): xt | x_edge | ctr | srcA | srcB | flatB | cntB
    bf16* xt = (bf16*)d_ws;                                   // 10.24 MB
    bf16* x_edge = xt + (size_t)BB * NN * CC;                 // 10.24 MB
    int* ctr = (int*)(x_edge + (size_t)BB * MM * CC);         // 2.56 MB
    u16* srcA = (u16*)(ctr + NCOPY * (BM + BN));              // 10.24 MB
    u16* srcB = srcA + (size_t)NCOPY * BM * CAPX;             // 10.24 MB
    u16* flatB = srcB + (size_t)NCOPY * BN * CAPX;            // 5.12 MB
    int* cntB = (int*)(flatB + (size_t)BN * 64);              // 0.16 MB

    hipMemsetAsync(ctr, 0, (size_t)NCOPY * (BM + BN) * sizeof(int), stream);

    build_gemm_k<<<1888, 256, 0, stream>>>(H, ctr, srcA, srcB, x, theta, xt);
    phase1_pull<<<BM / 4, 256, 0, stream>>>(xt, ctr, srcA, srcB, flatB, cntB, x_edge);
    phase2_pull<<<BN / 4, 256, 0, stream>>>(x_edge, flatB, cntB, bias, out);
}